// Round 9
// baseline (176.703 us; speedup 1.0000x reference)
//
#include <hip/hip_runtime.h>
#include <hip/hip_bf16.h>
#include <cmath>
#include <cstring>

#define B_TOT 16384

typedef unsigned int uint_t;
typedef unsigned short ushort_t;
typedef __attribute__((ext_vector_type(8))) short bf16x8;
typedef __attribute__((ext_vector_type(16))) float f32x16;

// workspace layout (bytes); total 10227712 (~9.76 MiB)
#define WS_TAB 0          // uint32[192] (kept for prep convenience)
#define WS_CSQ 1024       // double[64]
#define WS_LIN 4096       // 2 halves x float[16384][64] = 8 MiB (gemm -> tail)
#define WS_S   8392704    // float[64][4096] = 1 MiB (prep_s -> prep_pack)
#define WS_PPK 9441280    // A-packs: 192 steps * 4 KiB = 786432
#define LIN_HALF (B_TOT * 64)
// pack frag addr: ((s*4 + mt*2 + plane)*64 + lane)*16 ; plane 0=hi 1=lo
// lane (r=lane&31,h=lane>>5) holds P[n=mt*32+r][kappa = s*16 + h*8 + e]

// step decode (closed form, matches prep_pack's table):
//   s<64:   mode0 i=s>>2        p0=16*(s&3)
//   s<112:  mode0 i=16+q/3      p0=16*(1+q%3)   q=s-64
//   s<144:  mode0 i=32+(q>>1)   p0=16*(2+(q&1)) q=s-112
//   s<160:  mode0 i=48+(s-144)  p0=48
//   s<176:  mode1 p0=(s-160)*16
//   s<180:  mode2 p0=(s-176)*16
//   s==180: mode3
//   s>180:  mode2 p0=0 (A-pack zeroed)
__device__ __forceinline__ void decode_step(int s, int& mode, int& i_idx, int& p0) {
  if (s < 64) { mode = 0; i_idx = s >> 2; p0 = (s & 3) * 16; }
  else if (s < 112) { const int q = s - 64, qd = q / 3; mode = 0; i_idx = 16 + qd; p0 = 16 * (1 + (q - 3 * qd)); }
  else if (s < 144) { const int q = s - 112; mode = 0; i_idx = 32 + (q >> 1); p0 = 16 * (2 + (q & 1)); }
  else if (s < 160) { mode = 0; i_idx = 48 + (s - 144); p0 = 48; }
  else if (s < 176) { mode = 1; i_idx = 0; p0 = (s - 160) * 16; }
  else if (s < 180) { mode = 2; i_idx = 0; p0 = (s - 176) * 16; }
  else if (s == 180) { mode = 3; i_idx = 0; p0 = 0; }
  else { mode = 2; i_idx = 0; p0 = 0; }
}

// ---------- prep 1: S[n][cell] = sum_k cq[n,k]*gamma[k][cell] (LDS-staged) ----
__global__ __launch_bounds__(256) void prep_s(const float* __restrict__ g,
                                              const float* __restrict__ cq,
                                              char* __restrict__ ws) {
  __shared__ float gl[128][68];
  __shared__ float cql[16][132];
  float* S = (float*)(ws + WS_S);
  const int ns = blockIdx.x >> 6, J = blockIdx.x & 63, t = threadIdx.x;
  for (int i = t; i < 2048; i += 256) {
    const int k = i >> 4, c4 = (i & 15) * 4;
    *(float4*)&gl[k][c4] = *(const float4*)(g + (size_t)k * 4096 + J * 64 + c4);
  }
  for (int i = t; i < 2048; i += 256) {
    const int n16 = i >> 7, k = i & 127;
    cql[n16][k] = cq[(ns * 16 + n16) * 128 + k];
  }
  __syncthreads();
  const int n16 = t >> 4, c4 = (t & 15) * 4;
  float4 acc = {0.f, 0.f, 0.f, 0.f};
#pragma unroll 8
  for (int k = 0; k < 128; ++k) {
    const float w = cql[n16][k];
    const float4 gv = *(const float4*)&gl[k][c4];
    acc.x = fmaf(w, gv.x, acc.x);
    acc.y = fmaf(w, gv.y, acc.y);
    acc.z = fmaf(w, gv.z, acc.z);
    acc.w = fmaf(w, gv.w, acc.w);
  }
  *(float4*)(S + (size_t)(ns * 16 + n16) * 4096 + J * 64 + c4) = acc;
}

// ---------- prep 2: build bf16 hi/lo A-packs + tab + csq (256 blocks) --------
__global__ __launch_bounds__(256) void prep_pack(
    const float* __restrict__ qfw, const float* __restrict__ cq,
    const float* __restrict__ qzw, const float* __restrict__ qzb,
    const float* __restrict__ qfb, char* __restrict__ ws) {
  __shared__ float Sl[4096];
  __shared__ uint_t tabl[192];
  __shared__ float psumf[128][2];
  const int n = blockIdx.x & 63, part = blockIdx.x >> 6, t = threadIdx.x;
  const float* __restrict__ S = (const float*)(ws + WS_S) + (size_t)n * 4096;
  for (int i = t; i < 4096; i += 256) Sl[i] = S[i];
  if (t < 64) {
    const int i = t;
    const int start = (i < 16) ? 4 * i
                     : (i < 32) ? 64 + 3 * (i - 16)
                     : (i < 48) ? 112 + 2 * (i - 32)
                                : 144 + (i - 48);
    const int nst = 4 - (i >> 4);
    for (int u = 0; u < nst; ++u)
      tabl[start + u] = (0u << 16) | ((uint_t)i << 8) | (uint_t)(16 * ((i >> 4) + u));
  } else if (t < 80) tabl[160 + (t - 64)] = (1u << 16) | (uint_t)((t - 64) * 16);
  else if (t < 84)   tabl[176 + (t - 80)] = (2u << 16) | (uint_t)((t - 80) * 16);
  else if (t == 84)  tabl[180] = (3u << 16);
  else if (t < 96)   tabl[181 + (t - 85)] = 0;
  __syncthreads();
  if (part == 0 && n == 0 && t < 192) ((uint_t*)(ws + WS_TAB))[t] = tabl[t];

  const int mt = n >> 5, r = n & 31;
  auto wpack = [&](int s, int jo, float val) {
    const __hip_bfloat16 hb = __float2bfloat16(val);
    const float hf = __bfloat162float(hb);
    const __hip_bfloat16 lb = __float2bfloat16(val - hf);
    ushort_t hu, lu;
    memcpy(&hu, &hb, 2);
    memcpy(&lu, &lb, 2);
    const size_t base =
        (((size_t)s * 4 + mt * 2) * 64 + ((jo >> 3) & 1) * 32 + r) * 16 + (jo & 7) * 2;
    *(ushort_t*)(ws + WS_PPK + base) = hu;
    *(ushort_t*)(ws + WS_PPK + base + 1024) = lu;
  };

  for (int v = part * 640 + t; v < (part + 1) * 640; v += 256) {
    const int s = v >> 4, jo = v & 15;
    const uint_t inf = tabl[s];
    const int i = (inf >> 8) & 255, j0 = inf & 255;
    const int j = j0 + jo;
    const float val =
        (j < i) ? 0.f : ((j > i) ? Sl[i * 64 + j] + Sl[j * 64 + i] : Sl[i * 64 + i]);
    wpack(s, jo, val);
  }
  const float* __restrict__ cqn = cq + n * 128;

  if (part >= 2) {
    const int fl = t & 127, kh = t >> 7;
    const int f = (part - 2) * 128 + fl;
    float a = 0.f;
#pragma unroll 8
    for (int k = 0; k < 64; ++k)
      a = fmaf(qfw[(kh * 64 + k) * 256 + f], cqn[kh * 64 + k], a);
    psumf[fl][kh] = a;
    __syncthreads();
    if (t < 128) {
      const int ff = (part - 2) * 128 + t;
      wpack(160 + (ff >> 4), ff & 15, psumf[t][0] + psumf[t][1]);
    }
  } else if (part == 1) {
    if (t < 64) {
      float a = 0.f;
#pragma unroll 8
      for (int k = 0; k < 128; ++k) a = fmaf(cqn[k], qzw[k * 64 + t], a);
      wpack(176 + (t >> 4), t & 15, a);
    }
    for (int v2 = t; v2 < 176; v2 += 256) wpack(181 + (v2 >> 4), v2 & 15, 0.f);
  } else {
    if (t == 128) {
      float a = 0.f;
      for (int k = 0; k < 128; ++k) a = fmaf(qzb[k] + qfb[k], cqn[k], a);
      wpack(180, 0, a);
    } else if (t > 128 && t < 144) wpack(180, t - 128, 0.f);
    if (t == 144) {
      double a = 0.0;
      for (int d = 0; d < 64; ++d) a = fma((double)cqn[d], (double)cqn[d], a);
      ((double*)(ws + WS_CSQ))[n] = a;
    }
  }
}

// ---------- GEMM kernel: 1024 blocks x 256 thr, 32 rows, K-split 2 ----------
// ksl = blockIdx&1 selects half the steps; partials go to separate buffers
// (deterministic sum in tail). Arithmetic step decode: no tab[] load in the
// K-loop critical path. 4 blocks/CU = 4 waves/SIMD.
__global__ __launch_bounds__(256, 5) void gemm_kernel(
    const float* __restrict__ z, const float* __restrict__ feat,
    char* __restrict__ ws) {
  __shared__ __align__(16) unsigned char smem[17024];
  float (*z_lds)[68] = (float (*)[68])(smem);         // 8704
  float (*s_lin)[65] = (float (*)[65])(smem + 8704);  // 8320 -> 17024

  const int t = threadIdx.x, lane = t & 63;
  const int wv = __builtin_amdgcn_readfirstlane(t >> 6);  // 0..3
  const int ksl = blockIdx.x & 1;
  const int b0 = (blockIdx.x >> 1) * 32;
  const int h = lane >> 5, c = lane & 31;

  for (int i = t; i < 2048; i += 256) z_lds[i >> 6][i & 63] = z[(size_t)b0 * 64 + i];
  if (t < 128) z_lds[t >> 2][64 + (t & 3)] = 0.f;
  for (int i = t; i < 32 * 65; i += 256) ((float*)s_lin)[i] = 0.f;
  __syncthreads();

  const bf16x8* __restrict__ pp = (const bf16x8*)(ws + WS_PPK);
  f32x16 acc[2] = {};
#pragma unroll 2
  for (int it = 0; it < 24; ++it) {  // s = ksl*4 + wv + 8*it covers [0,192)
    const int s = ksl * 4 + wv + it * 8;
    int mode, i_idx, p0;
    decode_step(s, mode, i_idx, p0);
    const bf16x8 Ah0 = pp[((size_t)s * 4 + 0) * 64 + lane];
    const bf16x8 Al0 = pp[((size_t)s * 4 + 1) * 64 + lane];
    const bf16x8 Ah1 = pp[((size_t)s * 4 + 2) * 64 + lane];
    const bf16x8 Al1 = pp[((size_t)s * 4 + 3) * 64 + lane];
    const int bl = c;
    float xv[8];
    if (mode == 0) {
      const float zi = z_lds[bl][i_idx];
      const float* __restrict__ zp = &z_lds[bl][p0 + h * 8];
      const float4 a = *(const float4*)zp, b2 = *(const float4*)(zp + 4);
      xv[0] = zi * a.x; xv[1] = zi * a.y; xv[2] = zi * a.z; xv[3] = zi * a.w;
      xv[4] = zi * b2.x; xv[5] = zi * b2.y; xv[6] = zi * b2.z; xv[7] = zi * b2.w;
    } else if (mode == 1) {
      const float* __restrict__ fp = feat + (size_t)(b0 + bl) * 256 + p0 + h * 8;
      const float4 a = *(const float4*)fp, b2 = *(const float4*)(fp + 4);
      xv[0] = a.x; xv[1] = a.y; xv[2] = a.z; xv[3] = a.w;
      xv[4] = b2.x; xv[5] = b2.y; xv[6] = b2.z; xv[7] = b2.w;
    } else if (mode == 2) {
      const float* __restrict__ zp = &z_lds[bl][p0 + h * 8];
      const float4 a = *(const float4*)zp, b2 = *(const float4*)(zp + 4);
      xv[0] = a.x; xv[1] = a.y; xv[2] = a.z; xv[3] = a.w;
      xv[4] = b2.x; xv[5] = b2.y; xv[6] = b2.z; xv[7] = b2.w;
    } else {
      xv[0] = (h == 0) ? 1.f : 0.f;
      xv[1] = xv[2] = xv[3] = xv[4] = xv[5] = xv[6] = xv[7] = 0.f;
    }
    // RNE hi/lo split
    uint_t bhw[4], blw[4];
#pragma unroll
    for (int e2 = 0; e2 < 4; ++e2) {
      const float2 xp = {xv[2 * e2], xv[2 * e2 + 1]};
      const __hip_bfloat162 hb2 = __float22bfloat162_rn(xp);
      uint_t hw;
      memcpy(&hw, &hb2, 4);
      const float h0 = __uint_as_float(hw << 16);
      const float h1 = __uint_as_float(hw & 0xffff0000u);
      const float2 lp = {xp.x - h0, xp.y - h1};
      const __hip_bfloat162 lb2 = __float22bfloat162_rn(lp);
      uint_t lw;
      memcpy(&lw, &lb2, 4);
      bhw[e2] = hw;
      blw[e2] = lw;
    }
    bf16x8 Bh, Bl;
    memcpy(&Bh, bhw, 16);
    memcpy(&Bl, blw, 16);
    acc[0] = __builtin_amdgcn_mfma_f32_32x32x16_bf16(Ah0, Bh, acc[0], 0, 0, 0);
    acc[0] = __builtin_amdgcn_mfma_f32_32x32x16_bf16(Ah0, Bl, acc[0], 0, 0, 0);
    acc[0] = __builtin_amdgcn_mfma_f32_32x32x16_bf16(Al0, Bh, acc[0], 0, 0, 0);
    acc[1] = __builtin_amdgcn_mfma_f32_32x32x16_bf16(Ah1, Bh, acc[1], 0, 0, 0);
    acc[1] = __builtin_amdgcn_mfma_f32_32x32x16_bf16(Ah1, Bl, acc[1], 0, 0, 0);
    acc[1] = __builtin_amdgcn_mfma_f32_32x32x16_bf16(Al1, Bh, acc[1], 0, 0, 0);
  }
  // fold K-split partials: C layout col=lane&31, row=(r&3)+8*(r>>2)+4*h
#pragma unroll
  for (int mt = 0; mt < 2; ++mt)
#pragma unroll
    for (int r = 0; r < 16; ++r) {
      const int n = mt * 32 + (r & 3) + 8 * (r >> 2) + 4 * h;
      atomicAdd(&s_lin[c][n], acc[mt][r]);
    }
  __syncthreads();
  float* __restrict__ gl =
      (float*)(ws + WS_LIN) + (size_t)ksl * LIN_HALF + (size_t)b0 * 64;
  for (int i = t; i < 2048; i += 256) gl[i] = s_lin[i >> 6][i & 63];
}

// ---------- tail kernel: 1024 blocks x 256 thr, 16 rows/block ---------------
// thread = (row r = t&15, colgroup cg = t>>4); n = cg + 16u, u<4.
__global__ __launch_bounds__(256, 4) void tail_kernel(
    const float* __restrict__ z, const float* __restrict__ cq,
    const char* __restrict__ ws, float* __restrict__ out) {
  __shared__ __align__(16) unsigned char smem[28736];
  float (*zt)[17] = (float (*)[17])(smem);               // 64x17x4 = 4352
  float (*slin)[65] = (float (*)[65])(smem + 4352);      // 16x65x4 = 4160 -> 8512
  float (*cqT)[65] = (float (*)[65])(smem + 8512);       // 64x65x4 = 16640 -> 25152
  double (*s_exp)[65] = (double (*)[65])(smem + 8512);   // overlay cqT (8320)
  double (*pmax)[17] = (double (*)[17])(smem + 25152);   // 2176 -> 27328
  int (*parg)[17] = (int (*)[17])(smem + 27328);         // 1088 -> 28416
  double* rowmax = (double*)(smem + 28416);              // 128 -> 28544
  int* rowarg = (int*)(smem + 28544);                    // 64 -> 28608
  double* rowinv = (double*)(smem + 28608);              // 128 -> 28736

  const int t = threadIdx.x;
  const int r = t & 15, cg = t >> 4;  // 16 rows x 16 colgroups
  const int b0 = blockIdx.x * 16;
  const float* __restrict__ l0 = (const float*)(ws + WS_LIN) + (size_t)b0 * 64;
  const float* __restrict__ l1 = l0 + LIN_HALF;

  for (int i = t; i < 1024; i += 256) {
    zt[i & 63][i >> 6] = z[(size_t)b0 * 64 + i];
    slin[i >> 6][i & 63] = l0[i] + l1[i];
  }
  for (int i = t; i < 4096; i += 256) {
    const int n = i >> 6, ii = i & 63;
    cqT[ii][n] = cq[n * 128 + ii];
  }
  __syncthreads();

  // 5 parallel fp64 chains: z_sq + 4 z.c dots; zt/cqT reads broadcast (free)
  double z_sq = 0.0, zc[4] = {0.0, 0.0, 0.0, 0.0};
#pragma unroll 8
  for (int i = 0; i < 64; ++i) {
    const double zv = (double)zt[i][r];
    z_sq = fma(zv, zv, z_sq);
#pragma unroll
    for (int u = 0; u < 4; ++u)
      zc[u] = fma(zv, (double)cqT[i][cg + 16 * u], zc[u]);
  }
  float lin[4];
#pragma unroll
  for (int u = 0; u < 4; ++u) lin[u] = slin[r][cg + 16 * u];

  const double EPS = 0.001;
  const double SQRTK = sqrt(128.0);
  double tau = SQRTK * fmax(1.0 - z_sq, 0.001) * 0.5;
  tau = fmax(tau, 0.01);
  const double inv_tau = 1.0 / tau;
  const double r2 = fmin(z_sq, 1.0 - EPS);
  const double lam_fac = (1.0 - r2 + EPS) * 0.5 / SQRTK;  // (1/lam)/sqrt(K)
  const double* __restrict__ csqd = (const double*)(ws + WS_CSQ);

  double sc[4];
#pragma unroll
  for (int u = 0; u < 4; ++u) {
    const int n = cg + 16 * u;
    const double c_sq = csqd[n];
    const double dist_sq = z_sq + c_sq - 2.0 * zc[u];
    const double denom = (1.0 - z_sq) * (1.0 - c_sq);
    double arg = 1.0 + 2.0 * dist_sq / (denom + EPS);
    arg = fmax(arg, 1.0 + EPS);
    const double dist = log(arg + sqrt(arg * arg - 1.0));
    sc[u] = -dist * inv_tau + (double)lin[u] * lam_fac;
  }
  __syncthreads();  // all cqT/zt/slin reads done before s_exp overlay

  // per-thread max over ascending n (strict '>' keeps lowest index)
  {
    double mx = sc[0];
    int am = cg;
#pragma unroll
    for (int u = 1; u < 4; ++u)
      if (sc[u] > mx) { mx = sc[u]; am = cg + 16 * u; }
    pmax[r][cg] = mx;
    parg[r][cg] = am;
  }
  __syncthreads();
  if (t < 16) {
    double m = pmax[t][0];
    int a = parg[t][0];
#pragma unroll
    for (int g = 1; g < 16; ++g) {
      const double v = pmax[t][g];
      const int aa = parg[t][g];
      if (v > m || (v == m && aa < a)) { m = v; a = aa; }
    }
    rowmax[t] = m;
    rowarg[t] = a;
  }
  __syncthreads();
  {
    const double m = rowmax[r];
    double ps = 0.0;
#pragma unroll
    for (int u = 0; u < 4; ++u) {
      const double e = exp(sc[u] - m);
      s_exp[r][cg + 16 * u] = e;
      ps += e;
    }
    pmax[r][cg] = ps;
  }
  __syncthreads();
  if (t < 16) {
    double s = 0.0;
#pragma unroll
    for (int g = 0; g < 16; ++g) s += pmax[t][g];
    rowinv[t] = 1.0 / s;
  }
  __syncthreads();
  for (int idx = t; idx < 1024; idx += 256) {
    const int b = idx >> 6, n = idx & 63;
    out[(size_t)(b0 + b) * 64 + n] = (float)(s_exp[b][n] * rowinv[b]);
  }
  if (t < 16) out[(size_t)B_TOT * 64 + b0 + t] = (float)rowarg[t];
}

extern "C" void kernel_launch(void* const* d_in, const int* in_sizes, int n_in,
                              void* d_out, int out_size, void* d_ws, size_t ws_size,
                              hipStream_t stream) {
  const float* z = (const float*)d_in[0];
  const float* feat = (const float*)d_in[1];
  const float* qzw = (const float*)d_in[2];
  const float* qzb = (const float*)d_in[3];
  const float* qfw = (const float*)d_in[4];
  const float* qfb = (const float*)d_in[5];
  const float* gamma = (const float*)d_in[6];
  const float* cq = (const float*)d_in[7];
  float* out = (float*)d_out;
  char* ws = (char*)d_ws;  // requires ws_size >= 10227712

  prep_s<<<dim3(256), dim3(256), 0, stream>>>(gamma, cq, ws);
  prep_pack<<<dim3(256), dim3(256), 0, stream>>>(qfw, cq, qzw, qzb, qfb, ws);
  gemm_kernel<<<dim3(1024), dim3(256), 0, stream>>>(z, feat, ws);
  tail_kernel<<<dim3(1024), dim3(256), 0, stream>>>(z, cq, ws, out);
}

// Round 10
// 161.377 us; speedup vs baseline: 1.0950x; 1.0950x over previous
//
#include <hip/hip_runtime.h>
#include <hip/hip_bf16.h>
#include <cmath>
#include <cstring>

#define B_TOT 16384

typedef unsigned int uint_t;
typedef unsigned short ushort_t;
typedef __attribute__((ext_vector_type(8))) short bf16x8;
typedef __attribute__((ext_vector_type(16))) float f32x16;

// workspace layout (bytes); total 6033408 (~5.76 MiB)
#define WS_TAB 0          // uint32[192] (prep-internal)
#define WS_CSQ 1024       // double[64]
#define WS_LIN 4096       // float[16384][64] = 4 MiB (gemm -> tail)
#define WS_S   4198400    // float[64][4096] = 1 MiB (prep_s -> prep_pack)
#define WS_PPK 5246976    // A-packs: 192 steps * 4 KiB = 786432
// pack frag addr: ((s*4 + mt*2 + plane)*64 + lane)*16 ; plane 0=hi 1=lo
// lane (r=lane&31,h=lane>>5) holds P[n=mt*32+r][kappa = s*16 + h*8 + e]

// step decode (closed form):
__device__ __forceinline__ void decode_step(int s, int& mode, int& i_idx, int& p0) {
  if (s < 64) { mode = 0; i_idx = s >> 2; p0 = (s & 3) * 16; }
  else if (s < 112) { const int q = s - 64, qd = q / 3; mode = 0; i_idx = 16 + qd; p0 = 16 * (1 + (q - 3 * qd)); }
  else if (s < 144) { const int q = s - 112; mode = 0; i_idx = 32 + (q >> 1); p0 = 16 * (2 + (q & 1)); }
  else if (s < 160) { mode = 0; i_idx = 48 + (s - 144); p0 = 48; }
  else if (s < 176) { mode = 1; i_idx = 0; p0 = (s - 160) * 16; }
  else if (s < 180) { mode = 2; i_idx = 0; p0 = (s - 176) * 16; }
  else if (s == 180) { mode = 3; i_idx = 0; p0 = 0; }
  else { mode = 2; i_idx = 0; p0 = 0; }
}

// ---------- prep 1: S[n][cell] = sum_k cq[n,k]*gamma[k][cell] (LDS-staged) ----
__global__ __launch_bounds__(256) void prep_s(const float* __restrict__ g,
                                              const float* __restrict__ cq,
                                              char* __restrict__ ws) {
  __shared__ float gl[128][68];
  __shared__ float cql[16][132];
  float* S = (float*)(ws + WS_S);
  const int ns = blockIdx.x >> 6, J = blockIdx.x & 63, t = threadIdx.x;
  for (int i = t; i < 2048; i += 256) {
    const int k = i >> 4, c4 = (i & 15) * 4;
    *(float4*)&gl[k][c4] = *(const float4*)(g + (size_t)k * 4096 + J * 64 + c4);
  }
  for (int i = t; i < 2048; i += 256) {
    const int n16 = i >> 7, k = i & 127;
    cql[n16][k] = cq[(ns * 16 + n16) * 128 + k];
  }
  __syncthreads();
  const int n16 = t >> 4, c4 = (t & 15) * 4;
  float4 acc = {0.f, 0.f, 0.f, 0.f};
#pragma unroll 8
  for (int k = 0; k < 128; ++k) {
    const float w = cql[n16][k];
    const float4 gv = *(const float4*)&gl[k][c4];
    acc.x = fmaf(w, gv.x, acc.x);
    acc.y = fmaf(w, gv.y, acc.y);
    acc.z = fmaf(w, gv.z, acc.z);
    acc.w = fmaf(w, gv.w, acc.w);
  }
  *(float4*)(S + (size_t)(ns * 16 + n16) * 4096 + J * 64 + c4) = acc;
}

// ---------- prep 2: build bf16 hi/lo A-packs + csq (256 blocks) --------------
__global__ __launch_bounds__(256) void prep_pack(
    const float* __restrict__ qfw, const float* __restrict__ cq,
    const float* __restrict__ qzw, const float* __restrict__ qzb,
    const float* __restrict__ qfb, char* __restrict__ ws) {
  __shared__ float Sl[4096];
  __shared__ uint_t tabl[192];
  __shared__ float psumf[128][2];
  const int n = blockIdx.x & 63, part = blockIdx.x >> 6, t = threadIdx.x;
  const float* __restrict__ S = (const float*)(ws + WS_S) + (size_t)n * 4096;
  for (int i = t; i < 4096; i += 256) Sl[i] = S[i];
  if (t < 64) {
    const int i = t;
    const int start = (i < 16) ? 4 * i
                     : (i < 32) ? 64 + 3 * (i - 16)
                     : (i < 48) ? 112 + 2 * (i - 32)
                                : 144 + (i - 48);
    const int nst = 4 - (i >> 4);
    for (int u = 0; u < nst; ++u)
      tabl[start + u] = (0u << 16) | ((uint_t)i << 8) | (uint_t)(16 * ((i >> 4) + u));
  } else if (t < 80) tabl[160 + (t - 64)] = (1u << 16) | (uint_t)((t - 64) * 16);
  else if (t < 84)   tabl[176 + (t - 80)] = (2u << 16) | (uint_t)((t - 80) * 16);
  else if (t == 84)  tabl[180] = (3u << 16);
  else if (t < 96)   tabl[181 + (t - 85)] = 0;
  __syncthreads();

  const int mt = n >> 5, r = n & 31;
  auto wpack = [&](int s, int jo, float val) {
    const __hip_bfloat16 hb = __float2bfloat16(val);
    const float hf = __bfloat162float(hb);
    const __hip_bfloat16 lb = __float2bfloat16(val - hf);
    ushort_t hu, lu;
    memcpy(&hu, &hb, 2);
    memcpy(&lu, &lb, 2);
    const size_t base =
        (((size_t)s * 4 + mt * 2) * 64 + ((jo >> 3) & 1) * 32 + r) * 16 + (jo & 7) * 2;
    *(ushort_t*)(ws + WS_PPK + base) = hu;
    *(ushort_t*)(ws + WS_PPK + base + 1024) = lu;
  };

  for (int v = part * 640 + t; v < (part + 1) * 640; v += 256) {
    const int s = v >> 4, jo = v & 15;
    const uint_t inf = tabl[s];
    const int i = (inf >> 8) & 255, j0 = inf & 255;
    const int j = j0 + jo;
    const float val =
        (j < i) ? 0.f : ((j > i) ? Sl[i * 64 + j] + Sl[j * 64 + i] : Sl[i * 64 + i]);
    wpack(s, jo, val);
  }
  const float* __restrict__ cqn = cq + n * 128;

  if (part >= 2) {
    const int fl = t & 127, kh = t >> 7;
    const int f = (part - 2) * 128 + fl;
    float a = 0.f;
#pragma unroll 8
    for (int k = 0; k < 64; ++k)
      a = fmaf(qfw[(kh * 64 + k) * 256 + f], cqn[kh * 64 + k], a);
    psumf[fl][kh] = a;
    __syncthreads();
    if (t < 128) {
      const int ff = (part - 2) * 128 + t;
      wpack(160 + (ff >> 4), ff & 15, psumf[t][0] + psumf[t][1]);
    }
  } else if (part == 1) {
    if (t < 64) {
      float a = 0.f;
#pragma unroll 8
      for (int k = 0; k < 128; ++k) a = fmaf(cqn[k], qzw[k * 64 + t], a);
      wpack(176 + (t >> 4), t & 15, a);
    }
    for (int v2 = t; v2 < 176; v2 += 256) wpack(181 + (v2 >> 4), v2 & 15, 0.f);
  } else {
    if (t == 128) {
      float a = 0.f;
      for (int k = 0; k < 128; ++k) a = fmaf(qzb[k] + qfb[k], cqn[k], a);
      wpack(180, 0, a);
    } else if (t > 128 && t < 144) wpack(180, t - 128, 0.f);
    if (t == 144) {
      double a = 0.0;
      for (int d = 0; d < 64; ++d) a = fma((double)cqn[d], (double)cqn[d], a);
      ((double*)(ws + WS_CSQ))[n] = a;
    }
  }
}

// ---------- GEMM kernel: 512 blocks x 256 thr (4 waves), 32 rows ------------
// R8 shape + (a) feat tile in LDS, (b) branch-free B-build with const-row,
// (c) 3-buffer software-pipelined A-fragment prefetch (2 steps deep).
__global__ __launch_bounds__(256, 4) void gemm_kernel(
    const float* __restrict__ z, const float* __restrict__ feat,
    char* __restrict__ ws) {
  __shared__ __align__(16) unsigned char smem[50576];
  float (*z_lds)[68] = (float (*)[68])(smem);          // 33 rows: 8976 (row 32 = const row)
  float (*f_lds)[260] = (float (*)[260])(smem + 8976); // 33280 -> 42256
  float (*s_lin)[65] = (float (*)[65])(smem + 42256);  // 8320 -> 50576

  const int t = threadIdx.x, lane = t & 63;
  const int wv = __builtin_amdgcn_readfirstlane(t >> 6);  // 0..3
  const int b0 = blockIdx.x * 32;
  const int h8 = (lane >> 5) * 8, c = lane & 31;

  // stage z rows, const row, feat tile (coalesced float4), zero s_lin
  for (int i = t; i < 2048; i += 256) z_lds[i >> 6][i & 63] = z[(size_t)b0 * 64 + i];
  if (t < 64) z_lds[32][t] = (t == 0) ? 1.f : 0.f;
  for (int i = t; i < 2048; i += 256) {
    const int row = i >> 6, c4 = (i & 63) * 4;
    *(float4*)&f_lds[row][c4] = *(const float4*)(feat + (size_t)(b0 + row) * 256 + c4);
  }
  for (int i = t; i < 32 * 65; i += 256) ((float*)s_lin)[i] = 0.f;
  __syncthreads();

  const bf16x8* __restrict__ pp = (const bf16x8*)(ws + WS_PPK);
  f32x16 acc0 = {}, acc1 = {};

  auto load_A = [&](int s, bf16x8* A) {
    const bf16x8* __restrict__ base = pp + ((size_t)s * 4) * 64 + lane;
    A[0] = base[0];
    A[1] = base[64];
    A[2] = base[128];
    A[3] = base[192];
  };
  auto do_step = [&](const bf16x8* A, int s) {
    int mode, i_idx, p0;
    decode_step(s, mode, i_idx, p0);
    const float scale = (mode == 0) ? z_lds[c][i_idx] : 1.f;
    const float* __restrict__ row =
        (mode == 1) ? &f_lds[c][p0] : &z_lds[(mode == 3) ? 32 : c][p0];
    const float4 a = *(const float4*)(row + h8);
    const float4 b2 = *(const float4*)(row + h8 + 4);
    float xv[8] = {scale * a.x, scale * a.y, scale * a.z, scale * a.w,
                   scale * b2.x, scale * b2.y, scale * b2.z, scale * b2.w};
    uint_t bhw[4], blw[4];
#pragma unroll
    for (int e2 = 0; e2 < 4; ++e2) {
      const float2 xp = {xv[2 * e2], xv[2 * e2 + 1]};
      const __hip_bfloat162 hb2 = __float22bfloat162_rn(xp);
      uint_t hw;
      memcpy(&hw, &hb2, 4);
      const float h0 = __uint_as_float(hw << 16);
      const float h1 = __uint_as_float(hw & 0xffff0000u);
      const float2 lp = {xp.x - h0, xp.y - h1};
      const __hip_bfloat162 lb2 = __float22bfloat162_rn(lp);
      uint_t lw;
      memcpy(&lw, &lb2, 4);
      bhw[e2] = hw;
      blw[e2] = lw;
    }
    bf16x8 Bh, Bl;
    memcpy(&Bh, bhw, 16);
    memcpy(&Bl, blw, 16);
    acc0 = __builtin_amdgcn_mfma_f32_32x32x16_bf16(A[0], Bh, acc0, 0, 0, 0);
    acc0 = __builtin_amdgcn_mfma_f32_32x32x16_bf16(A[0], Bl, acc0, 0, 0, 0);
    acc0 = __builtin_amdgcn_mfma_f32_32x32x16_bf16(A[1], Bh, acc0, 0, 0, 0);
    acc1 = __builtin_amdgcn_mfma_f32_32x32x16_bf16(A[2], Bh, acc1, 0, 0, 0);
    acc1 = __builtin_amdgcn_mfma_f32_32x32x16_bf16(A[2], Bl, acc1, 0, 0, 0);
    acc1 = __builtin_amdgcn_mfma_f32_32x32x16_bf16(A[3], Bh, acc1, 0, 0, 0);
  };
  auto clamp_s = [](int s) { return s > 191 ? 191 : s; };

  // s = wv + 4*it, it = 0..47; 3-buffer rotation, prefetch depth = 2 steps
  bf16x8 A0[4], A1[4], A2[4];
  load_A(wv, A0);
  load_A(wv + 4, A1);
  load_A(wv + 8, A2);
#pragma unroll 1
  for (int it3 = 0; it3 < 16; ++it3) {
    const int s = wv + it3 * 12;
    do_step(A0, s);
    load_A(clamp_s(s + 12), A0);
    do_step(A1, s + 4);
    load_A(clamp_s(s + 16), A1);
    do_step(A2, s + 8);
    load_A(clamp_s(s + 20), A2);
  }

  // fold K-split partials: C layout col=lane&31, row=(r&3)+8*(r>>2)+4*h
#pragma unroll
  for (int r = 0; r < 16; ++r) {
    const int n0 = (r & 3) + 8 * (r >> 2) + 4 * (h8 >> 3);
    atomicAdd(&s_lin[c][n0], acc0[r]);
    atomicAdd(&s_lin[c][32 + n0], acc1[r]);
  }
  __syncthreads();
  float* __restrict__ gl = (float*)(ws + WS_LIN) + (size_t)b0 * 64;
  for (int i = t; i < 2048; i += 256) gl[i] = s_lin[i >> 6][i & 63];
}

// ---------- tail kernel: 1024 blocks x 256 thr, 16 rows/block ---------------
__global__ __launch_bounds__(256, 4) void tail_kernel(
    const float* __restrict__ z, const float* __restrict__ cq,
    const char* __restrict__ ws, float* __restrict__ out) {
  __shared__ __align__(16) unsigned char smem[28736];
  float (*zt)[17] = (float (*)[17])(smem);               // 4352
  float (*slin)[65] = (float (*)[65])(smem + 4352);      // 4160 -> 8512
  float (*cqT)[65] = (float (*)[65])(smem + 8512);       // 16640 -> 25152
  double (*s_exp)[65] = (double (*)[65])(smem + 8512);   // overlay cqT (8320)
  double (*pmax)[17] = (double (*)[17])(smem + 25152);   // 2176 -> 27328
  int (*parg)[17] = (int (*)[17])(smem + 27328);         // 1088 -> 28416
  double* rowmax = (double*)(smem + 28416);              // 128
  int* rowarg = (int*)(smem + 28544);                    // 64
  double* rowinv = (double*)(smem + 28608);              // 128 -> 28736

  const int t = threadIdx.x;
  const int r = t & 15, cg = t >> 4;
  const int b0 = blockIdx.x * 16;
  const float* __restrict__ l0 = (const float*)(ws + WS_LIN) + (size_t)b0 * 64;

  for (int i = t; i < 1024; i += 256) {
    zt[i & 63][i >> 6] = z[(size_t)b0 * 64 + i];
    slin[i >> 6][i & 63] = l0[i];
  }
  for (int i = t; i < 4096; i += 256) {
    const int n = i >> 6, ii = i & 63;
    cqT[ii][n] = cq[n * 128 + ii];
  }
  __syncthreads();

  double z_sq = 0.0, zc[4] = {0.0, 0.0, 0.0, 0.0};
#pragma unroll 8
  for (int i = 0; i < 64; ++i) {
    const double zv = (double)zt[i][r];
    z_sq = fma(zv, zv, z_sq);
#pragma unroll
    for (int u = 0; u < 4; ++u)
      zc[u] = fma(zv, (double)cqT[i][cg + 16 * u], zc[u]);
  }
  float lin[4];
#pragma unroll
  for (int u = 0; u < 4; ++u) lin[u] = slin[r][cg + 16 * u];

  const double EPS = 0.001;
  const double SQRTK = sqrt(128.0);
  double tau = SQRTK * fmax(1.0 - z_sq, 0.001) * 0.5;
  tau = fmax(tau, 0.01);
  const double inv_tau = 1.0 / tau;
  const double r2 = fmin(z_sq, 1.0 - EPS);
  const double lam_fac = (1.0 - r2 + EPS) * 0.5 / SQRTK;
  const double* __restrict__ csqd = (const double*)(ws + WS_CSQ);

  double sc[4];
#pragma unroll
  for (int u = 0; u < 4; ++u) {
    const int n = cg + 16 * u;
    const double c_sq = csqd[n];
    const double dist_sq = z_sq + c_sq - 2.0 * zc[u];
    const double denom = (1.0 - z_sq) * (1.0 - c_sq);
    double arg = 1.0 + 2.0 * dist_sq / (denom + EPS);
    arg = fmax(arg, 1.0 + EPS);
    const double dist = log(arg + sqrt(arg * arg - 1.0));
    sc[u] = -dist * inv_tau + (double)lin[u] * lam_fac;
  }
  __syncthreads();

  {
    double mx = sc[0];
    int am = cg;
#pragma unroll
    for (int u = 1; u < 4; ++u)
      if (sc[u] > mx) { mx = sc[u]; am = cg + 16 * u; }
    pmax[r][cg] = mx;
    parg[r][cg] = am;
  }
  __syncthreads();
  if (t < 16) {
    double m = pmax[t][0];
    int a = parg[t][0];
#pragma unroll
    for (int g = 1; g < 16; ++g) {
      const double v = pmax[t][g];
      const int aa = parg[t][g];
      if (v > m || (v == m && aa < a)) { m = v; a = aa; }
    }
    rowmax[t] = m;
    rowarg[t] = a;
  }
  __syncthreads();
  {
    const double m = rowmax[r];
    double ps = 0.0;
#pragma unroll
    for (int u = 0; u < 4; ++u) {
      const double e = exp(sc[u] - m);
      s_exp[r][cg + 16 * u] = e;
      ps += e;
    }
    pmax[r][cg] = ps;
  }
  __syncthreads();
  if (t < 16) {
    double s = 0.0;
#pragma unroll
    for (int g = 0; g < 16; ++g) s += pmax[t][g];
    rowinv[t] = 1.0 / s;
  }
  __syncthreads();
  for (int idx = t; idx < 1024; idx += 256) {
    const int b = idx >> 6, n = idx & 63;
    out[(size_t)(b0 + b) * 64 + n] = (float)(s_exp[b][n] * rowinv[b]);
  }
  if (t < 16) out[(size_t)B_TOT * 64 + b0 + t] = (float)rowarg[t];
}

extern "C" void kernel_launch(void* const* d_in, const int* in_sizes, int n_in,
                              void* d_out, int out_size, void* d_ws, size_t ws_size,
                              hipStream_t stream) {
  const float* z = (const float*)d_in[0];
  const float* feat = (const float*)d_in[1];
  const float* qzw = (const float*)d_in[2];
  const float* qzb = (const float*)d_in[3];
  const float* qfw = (const float*)d_in[4];
  const float* qfb = (const float*)d_in[5];
  const float* gamma = (const float*)d_in[6];
  const float* cq = (const float*)d_in[7];
  float* out = (float*)d_out;
  char* ws = (char*)d_ws;  // requires ws_size >= 6033408

  prep_s<<<dim3(256), dim3(256), 0, stream>>>(gamma, cq, ws);
  prep_pack<<<dim3(256), dim3(256), 0, stream>>>(qfw, cq, qzw, qzb, qfb, ws);
  gemm_kernel<<<dim3(512), dim3(256), 0, stream>>>(z, feat, ws);
  tail_kernel<<<dim3(1024), dim3(256), 0, stream>>>(z, cq, ws, out);
}